// Round 1
// baseline (9170.663 us; speedup 1.0000x reference)
//
#include <hip/hip_runtime.h>
#include <hip/hip_bf16.h>
#include <math.h>

#define BB 32
#define SS 256
#define EE 768
#define HH 512
#define GG 2048   // 4*H
#define NCLS 30

typedef __attribute__((ext_vector_type(8))) short bf16x8;
typedef __attribute__((ext_vector_type(4))) float f32x4;

__device__ inline unsigned short f2bf(float f) {
  union { float f; unsigned int u; } v; v.f = f;
  unsigned int r = v.u + 0x7fffu + ((v.u >> 16) & 1u);
  return (unsigned short)(r >> 16);
}
__device__ inline float bf2f(unsigned short u) {
  union { unsigned int u; float f; } v; v.u = ((unsigned int)u) << 16;
  return v.f;
}
__device__ inline float sigm(float x) { return 1.f / (1.f + expf(-x)); }

__device__ inline void load_lds16(const void* g, void* l) {
  __builtin_amdgcn_global_load_lds(
      (const __attribute__((address_space(1))) void*)g,
      (__attribute__((address_space(3))) void*)l, 16, 0, 0);
}

// ---------------- weight conversion (fp32 -> bf16, with K padding) ----------
__global__ void k_convpad(const float* __restrict__ src, unsigned short* __restrict__ dst,
                          int R, int Ks, int Kd) {
  int n = R * Kd;
  for (int i = blockIdx.x * blockDim.x + threadIdx.x; i < n; i += gridDim.x * blockDim.x) {
    int r = i / Kd, k = i - r * Kd;
    dst[i] = (k < Ks) ? f2bf(src[(size_t)r * Ks + k]) : (unsigned short)0;
  }
}

__global__ void k_biassum(const float* __restrict__ a, const float* __restrict__ b,
                          float* __restrict__ o) {
  int i = blockIdx.x * 256 + threadIdx.x;
  if (i < GG) o[i] = a[i] + b[i];
}

// ---------------- mean_word[b][s] = mean over (4 layers, 768) --------------
__global__ void k_meanword(const float* __restrict__ hs, float* __restrict__ mw) {
  int blk = blockIdx.x;           // b*256 + s
  int b = blk >> 8, s = blk & 255;
  __shared__ float red[256];
  size_t base = ((size_t)b * SS + s) * EE;
  const size_t LSTR = (size_t)BB * SS * EE;
  float acc = 0.f;
  for (int l = 0; l < 4; l++)
    for (int e = threadIdx.x; e < EE; e += 256) acc += hs[l * LSTR + base + e];
  red[threadIdx.x] = acc;
  __syncthreads();
  for (int s2 = 128; s2 > 0; s2 >>= 1) {
    if (threadIdx.x < s2) red[threadIdx.x] += red[threadIdx.x + s2];
    __syncthreads();
  }
  if (threadIdx.x == 0) mw[blk] = red[0] * (1.f / 3072.f);
}

// ---------------- idx_pred[b] = argmax (first max) of predicates -----------
__global__ void k_idxpred(const int* __restrict__ pred, int* __restrict__ idxp) {
  int b = blockIdx.x, l = threadIdx.x;  // 64 threads
  const int* pb = pred + b * SS;
  int4 v = *(const int4*)(pb + l * 4);
  int loc = 0x7fffffff;
  if (v.w == 1) loc = 4 * l + 3;
  if (v.z == 1) loc = 4 * l + 2;
  if (v.y == 1) loc = 4 * l + 1;
  if (v.x == 1) loc = 4 * l + 0;
  for (int off = 32; off > 0; off >>= 1) {
    int o = __shfl_down(loc, off);
    loc = min(loc, o);
  }
  if (l == 0) idxp[b] = (loc == 0x7fffffff) ? 0 : loc;
}

// ---------------- A0 [s*32+b][800] bf16 feature matrix ---------------------
__global__ void k_buildA0(const float* __restrict__ hs, const float* __restrict__ mw,
                          const int* __restrict__ idxp, const int* __restrict__ roles,
                          unsigned short* __restrict__ A0) {
  int blk = blockIdx.x;           // s*32 + b
  int s = blk >> 5, b = blk & 31;
  unsigned short* row = A0 + (size_t)blk * 800;
  size_t base = ((size_t)b * SS + s) * EE;
  const size_t LSTR = (size_t)BB * SS * EE;
  for (int k = threadIdx.x; k < EE; k += 256) {
    float v = hs[base + k] + hs[base + LSTR + k] + hs[base + 2 * LSTR + k] + hs[base + 3 * LSTR + k];
    row[k] = f2bf(v * 0.25f);
  }
  if (threadIdx.x == 0) {
    float d = mw[b * SS + s] - mw[b * SS + idxp[b]];
    row[768] = f2bf(d);
    int rl = roles[b * SS + s];
    row[769] = f2bf((rl != 0 && rl != -100) ? 1.f : 0.f);
  }
  if (threadIdx.x < 30) row[770 + threadIdx.x] = 0;
}

// ---------------- GEMM-BT: C[s][n][b] = A[s*32+b][:] . W[n][:] + bias[n] ---
// A: [8192, K] bf16 ; W: [2048, K] bf16 ; C: fp32 [256][2048][32]
__global__ __launch_bounds__(256) void k_gemm_bt(const unsigned short* __restrict__ A,
                                                 const unsigned short* __restrict__ W,
                                                 const float* __restrict__ bias,
                                                 float* __restrict__ C, int K) {
  __shared__ unsigned short As[128 * 32];
  __shared__ unsigned short Bs[128 * 32];
  const int tid = threadIdx.x;
  const int wave = tid >> 6, lane = tid & 63;
  const int l15 = lane & 15, quad = lane >> 4;
  const int m0 = blockIdx.y * 128, n0 = blockIdx.x * 128;
  const int wr = (wave >> 1) * 64, wc = (wave & 1) * 64;
  const int srow = wave * 16 + (lane >> 2);
  const int scol = (lane & 3) * 8;

  f32x4 acc[4][4];
#pragma unroll
  for (int i = 0; i < 4; i++)
#pragma unroll
    for (int j = 0; j < 4; j++) acc[i][j] = (f32x4){0.f, 0.f, 0.f, 0.f};

  for (int k0 = 0; k0 < K; k0 += 32) {
#pragma unroll
    for (int rep = 0; rep < 2; rep++) {
      load_lds16(A + (size_t)(m0 + rep * 64 + srow) * K + k0 + scol,
                 &As[(rep * 64 + wave * 16) * 32]);
      load_lds16(W + (size_t)(n0 + rep * 64 + srow) * K + k0 + scol,
                 &Bs[(rep * 64 + wave * 16) * 32]);
    }
    __syncthreads();
    bf16x8 af[4], bfr[4];
#pragma unroll
    for (int i = 0; i < 4; i++) af[i] = *(const bf16x8*)&As[(wr + i * 16 + l15) * 32 + quad * 8];
#pragma unroll
    for (int j = 0; j < 4; j++) bfr[j] = *(const bf16x8*)&Bs[(wc + j * 16 + l15) * 32 + quad * 8];
#pragma unroll
    for (int i = 0; i < 4; i++)
#pragma unroll
      for (int j = 0; j < 4; j++)
        acc[i][j] = __builtin_amdgcn_mfma_f32_16x16x32_bf16(af[i], bfr[j], acc[i][j], 0, 0, 0);
    __syncthreads();
  }

#pragma unroll
  for (int j = 0; j < 4; j++) {
    int n = n0 + wc + j * 16 + l15;
    float bv = bias[n];
#pragma unroll
    for (int i = 0; i < 4; i++) {
      int m = m0 + wr + i * 16 + quad * 4;  // row = s*32+b, 4 consecutive b
      int s = m >> 5, b = m & 31;
      f32x4 v = acc[i][j];
      f32x4 outv = {v[0] + bv, v[1] + bv, v[2] + bv, v[3] + bv};
      *(f32x4*)(C + ((size_t)s * GG + n) * BB + b) = outv;
    }
  }
}

// ---------------- persistent BiLSTM recurrence (one layer) ------------------
// 64 WGs: dir = wg>>5 (0 fwd, 1 bwd), slice = wg&31 -> hidden units [16*slice, +16)
// wave w handles gate type w (i,f,g,o) rows w*512 + u0 + [0,16)
__global__ __launch_bounds__(256) void k_recurrent(const float* __restrict__ xWf,
                                                   const float* __restrict__ xWb,
                                                   const unsigned short* __restrict__ WhhF,
                                                   const unsigned short* __restrict__ WhhB,
                                                   unsigned short* __restrict__ hbuf,
                                                   unsigned short* __restrict__ Hout,
                                                   int* __restrict__ counters) {
  const int wg = blockIdx.x, dir = wg >> 5, slice = wg & 31;
  const int tid = threadIdx.x, wave = tid >> 6, lane = tid & 63;
  const int l15 = lane & 15, quad = lane >> 4;
  const int u0 = slice * 16;
  const unsigned short* Whh = dir ? WhhB : WhhF;
  const float* xW = dir ? xWb : xWf;
  unsigned short* hb = hbuf + dir * (2 * BB * HH);
  int* cnt = counters + dir * 16;

  // Whh B-fragments resident in registers (N=16 rows, K=512)
  bf16x8 bfrag[16];
  const unsigned short* wrow = Whh + (size_t)(wave * HH + u0 + l15) * HH + quad * 8;
#pragma unroll
  for (int kk = 0; kk < 16; kk++) bfrag[kk] = *(const bf16x8*)(wrow + kk * 32);

  __shared__ float gbuf[4][32][16];  // [gate][batch][unit]
  const int cb = tid >> 3;           // batch this thread updates
  const int cu = (tid & 7) * 2;      // local unit pair
  float c0 = 0.f, c1 = 0.f;

  for (int t = 0; t < SS; t++) {
    const int par = t & 1;
    const int time = dir ? (SS - 1 - t) : t;
    const unsigned short* hsrc = hb + par * BB * HH;

    // prefetch xW slice (fp32, [time][gate_row][batch])
    const float* xwp = xW + ((size_t)time * GG + wave * HH + u0 + l15) * BB;
    f32x4 xv0 = *(const f32x4*)(xwp + quad * 4);
    f32x4 xv1 = *(const f32x4*)(xwp + 16 + quad * 4);

    f32x4 a0acc = {0.f, 0.f, 0.f, 0.f}, a1acc = {0.f, 0.f, 0.f, 0.f};
    const unsigned short* ap0 = hsrc + l15 * HH + quad * 8;
    const unsigned short* ap1 = hsrc + (16 + l15) * HH + quad * 8;
#pragma unroll
    for (int kk = 0; kk < 16; kk++) {
      bf16x8 a0 = *(const bf16x8*)(ap0 + kk * 32);
      bf16x8 a1 = *(const bf16x8*)(ap1 + kk * 32);
      a0acc = __builtin_amdgcn_mfma_f32_16x16x32_bf16(a0, bfrag[kk], a0acc, 0, 0, 0);
      a1acc = __builtin_amdgcn_mfma_f32_16x16x32_bf16(a1, bfrag[kk], a1acc, 0, 0, 0);
    }
#pragma unroll
    for (int r = 0; r < 4; r++) {
      gbuf[wave][quad * 4 + r][l15] = a0acc[r] + xv0[r];
      gbuf[wave][16 + quad * 4 + r][l15] = a1acc[r] + xv1[r];
    }
    __syncthreads();

    // cell update: thread owns (cb, u0+cu) and (cb, u0+cu+1)
    float gi0 = sigm(gbuf[0][cb][cu]), gi1 = sigm(gbuf[0][cb][cu + 1]);
    float gf0 = sigm(gbuf[1][cb][cu]), gf1 = sigm(gbuf[1][cb][cu + 1]);
    float gg0 = tanhf(gbuf[2][cb][cu]), gg1 = tanhf(gbuf[2][cb][cu + 1]);
    float go0 = sigm(gbuf[3][cb][cu]), go1 = sigm(gbuf[3][cb][cu + 1]);
    c0 = gf0 * c0 + gi0 * gg0;
    c1 = gf1 * c1 + gi1 * gg1;
    float h0 = go0 * tanhf(c0), h1 = go1 * tanhf(c1);
    unsigned int packed = (unsigned int)f2bf(h0) | ((unsigned int)f2bf(h1) << 16);
    *(unsigned int*)(hb + (1 - par) * BB * HH + cb * HH + u0 + cu) = packed;
    *(unsigned int*)(Hout + ((size_t)time * BB + cb) * 1024 + dir * HH + u0 + cu) = packed;

    // device-scope barrier over the 32 WGs of this direction
    __threadfence();
    __syncthreads();
    if (tid == 0) {
      __hip_atomic_fetch_add(cnt, 1, __ATOMIC_RELAXED, __HIP_MEMORY_SCOPE_AGENT);
      const int target = 32 * (t + 1);
      while (__hip_atomic_load(cnt, __ATOMIC_RELAXED, __HIP_MEMORY_SCOPE_AGENT) < target)
        __builtin_amdgcn_s_sleep(1);
    }
    __syncthreads();
    __threadfence();
  }
}

// ---------------- final linear: out[b][s][c] = H1[s*32+b][:] . Wout[c][:] + bout[c]
__global__ __launch_bounds__(256) void k_out(const unsigned short* __restrict__ H1,
                                             const float* __restrict__ Wout,
                                             const float* __restrict__ bout,
                                             float* __restrict__ out) {
  __shared__ float rows[8][1024];
  __shared__ float ps[8][32][8];  // [kpart][class][row]
  const int rb = blockIdx.x * 8;
  const int tid = threadIdx.x;
  for (int idx = tid; idx < 8 * 1024; idx += 256) {
    int r = idx >> 10, k = idx & 1023;
    rows[r][k] = bf2f(H1[(size_t)(rb + r) * 1024 + k]);
  }
  __syncthreads();
  const int c = tid & 31, p = tid >> 5;
  float acc[8] = {0.f, 0.f, 0.f, 0.f, 0.f, 0.f, 0.f, 0.f};
  if (c < NCLS) {
    const float* wr = Wout + (size_t)c * 1024 + p * 128;
    for (int k = 0; k < 128; k++) {
      float w = wr[k];
#pragma unroll
      for (int r = 0; r < 8; r++) acc[r] += rows[r][p * 128 + k] * w;
    }
  }
#pragma unroll
  for (int r = 0; r < 8; r++) ps[p][c][r] = acc[r];
  __syncthreads();
  if (p == 0 && c < NCLS) {
    for (int r = 0; r < 8; r++) {
      float v = bout[c];
#pragma unroll
      for (int q = 0; q < 8; q++) v += ps[q][c][r];
      int row = rb + r, s = row >> 5, b = row & 31;
      out[((size_t)b * SS + s) * NCLS + c] = v;
    }
  }
}

// ---------------------------------------------------------------------------
extern "C" void kernel_launch(void* const* d_in, const int* in_sizes, int n_in,
                              void* d_out, int out_size, void* d_ws, size_t ws_size,
                              hipStream_t stream) {
  const float* hs     = (const float*)d_in[0];
  const int*   roles  = (const int*)d_in[1];
  const int*   preds  = (const int*)d_in[2];
  const float* Wih0f  = (const float*)d_in[3];
  const float* Whh0f  = (const float*)d_in[4];
  const float* bih0f  = (const float*)d_in[5];
  const float* bhh0f  = (const float*)d_in[6];
  const float* Wih0b  = (const float*)d_in[7];
  const float* Whh0b  = (const float*)d_in[8];
  const float* bih0b  = (const float*)d_in[9];
  const float* bhh0b  = (const float*)d_in[10];
  const float* Wih1f  = (const float*)d_in[11];
  const float* Whh1f  = (const float*)d_in[12];
  const float* bih1f  = (const float*)d_in[13];
  const float* bhh1f  = (const float*)d_in[14];
  const float* Wih1b  = (const float*)d_in[15];
  const float* Whh1b  = (const float*)d_in[16];
  const float* bih1b  = (const float*)d_in[17];
  const float* bhh1b  = (const float*)d_in[18];
  const float* Wout   = (const float*)d_in[19];
  const float* bout   = (const float*)d_in[20];
  (void)in_sizes; (void)n_in; (void)out_size; (void)ws_size;

  char* ws = (char*)d_ws;
  size_t off = 0;
  auto alloc = [&](size_t bytes) -> char* {
    char* p = ws + off;
    off += (bytes + 255) & ~(size_t)255;
    return p;
  };
  float* xWf = (float*)alloc((size_t)SS * GG * BB * 4);       // 67.1 MB (reused L0/L1)
  float* xWb = (float*)alloc((size_t)SS * GG * BB * 4);       // 67.1 MB
  unsigned short* A0  = (unsigned short*)alloc((size_t)8192 * 800 * 2);
  unsigned short* H0p = (unsigned short*)alloc((size_t)8192 * 1024 * 2);
  unsigned short* H1p = (unsigned short*)alloc((size_t)8192 * 1024 * 2);
  unsigned short* Wb0f = (unsigned short*)alloc((size_t)GG * 800 * 2);
  unsigned short* Wb0b = (unsigned short*)alloc((size_t)GG * 800 * 2);
  unsigned short* Wb1f = (unsigned short*)alloc((size_t)GG * 1024 * 2);
  unsigned short* Wb1b = (unsigned short*)alloc((size_t)GG * 1024 * 2);
  unsigned short* Wh0f = (unsigned short*)alloc((size_t)GG * HH * 2);
  unsigned short* Wh0b = (unsigned short*)alloc((size_t)GG * HH * 2);
  unsigned short* Wh1f = (unsigned short*)alloc((size_t)GG * HH * 2);
  unsigned short* Wh1b = (unsigned short*)alloc((size_t)GG * HH * 2);
  float* bsum = (float*)alloc(4 * GG * 4);
  float* mw   = (float*)alloc((size_t)BB * SS * 4);
  int*   idxp = (int*)alloc(256);
  char*  zbase = alloc(131072 + 131072 + 512);
  unsigned short* hbuf0 = (unsigned short*)zbase;
  unsigned short* hbuf1 = (unsigned short*)(zbase + 131072);
  int* counters = (int*)(zbase + 262144);

  hipMemsetAsync(zbase, 0, 131072 + 131072 + 512, stream);

  k_convpad<<<1024, 256, 0, stream>>>(Wih0f, Wb0f, GG, 770, 800);
  k_convpad<<<1024, 256, 0, stream>>>(Wih0b, Wb0b, GG, 770, 800);
  k_convpad<<<1024, 256, 0, stream>>>(Wih1f, Wb1f, GG, 1024, 1024);
  k_convpad<<<1024, 256, 0, stream>>>(Wih1b, Wb1b, GG, 1024, 1024);
  k_convpad<<<1024, 256, 0, stream>>>(Whh0f, Wh0f, GG, 512, 512);
  k_convpad<<<1024, 256, 0, stream>>>(Whh0b, Wh0b, GG, 512, 512);
  k_convpad<<<1024, 256, 0, stream>>>(Whh1f, Wh1f, GG, 512, 512);
  k_convpad<<<1024, 256, 0, stream>>>(Whh1b, Wh1b, GG, 512, 512);
  k_biassum<<<8, 256, 0, stream>>>(bih0f, bhh0f, bsum);
  k_biassum<<<8, 256, 0, stream>>>(bih0b, bhh0b, bsum + 2048);
  k_biassum<<<8, 256, 0, stream>>>(bih1f, bhh1f, bsum + 4096);
  k_biassum<<<8, 256, 0, stream>>>(bih1b, bhh1b, bsum + 6144);

  k_meanword<<<BB * SS, 256, 0, stream>>>(hs, mw);
  k_idxpred<<<BB, 64, 0, stream>>>(preds, idxp);
  k_buildA0<<<BB * SS, 256, 0, stream>>>(hs, mw, idxp, roles, A0);

  dim3 gg(16, 64);
  k_gemm_bt<<<gg, 256, 0, stream>>>(A0, Wb0f, bsum, xWf, 800);
  k_gemm_bt<<<gg, 256, 0, stream>>>(A0, Wb0b, bsum + 2048, xWb, 800);
  k_recurrent<<<64, 256, 0, stream>>>(xWf, xWb, Wh0f, Wh0b, hbuf0, H0p, counters);
  k_gemm_bt<<<gg, 256, 0, stream>>>(H0p, Wb1f, bsum + 4096, xWf, 1024);
  k_gemm_bt<<<gg, 256, 0, stream>>>(H0p, Wb1b, bsum + 6144, xWb, 1024);
  k_recurrent<<<64, 256, 0, stream>>>(xWf, xWb, Wh1f, Wh1b, hbuf1, H1p, counters + 64);
  k_out<<<1024, 256, 0, stream>>>(H1p, Wout, bout, (float*)d_out);
}

// Round 2
// 7376.477 us; speedup vs baseline: 1.2432x; 1.2432x over previous
//
#include <hip/hip_runtime.h>
#include <hip/hip_bf16.h>
#include <math.h>

#define BB 32
#define SS 256
#define EE 768
#define HH 512
#define GG 2048   // 4*H
#define NCLS 30
#define NWG 16    // workgroups per LSTM direction

typedef __attribute__((ext_vector_type(8))) short bf16x8;
typedef __attribute__((ext_vector_type(4))) float f32x4;

__device__ inline unsigned short f2bf(float f) {
  union { float f; unsigned int u; } v; v.f = f;
  unsigned int r = v.u + 0x7fffu + ((v.u >> 16) & 1u);
  return (unsigned short)(r >> 16);
}
__device__ inline float bf2f(unsigned short u) {
  union { unsigned int u; float f; } v; v.u = ((unsigned int)u) << 16;
  return v.f;
}
__device__ inline float sigm(float x) { return 1.f / (1.f + expf(-x)); }

__device__ inline void load_lds16(const void* g, void* l) {
  __builtin_amdgcn_global_load_lds(
      (const __attribute__((address_space(1))) void*)g,
      (__attribute__((address_space(3))) void*)l, 16, 0, 0);
}

// ---------------- weight conversion (fp32 -> bf16, with K padding) ----------
__global__ void k_convpad(const float* __restrict__ src, unsigned short* __restrict__ dst,
                          int R, int Ks, int Kd) {
  int n = R * Kd;
  for (int i = blockIdx.x * blockDim.x + threadIdx.x; i < n; i += gridDim.x * blockDim.x) {
    int r = i / Kd, k = i - r * Kd;
    dst[i] = (k < Ks) ? f2bf(src[(size_t)r * Ks + k]) : (unsigned short)0;
  }
}

__global__ void k_biassum(const float* __restrict__ a, const float* __restrict__ b,
                          float* __restrict__ o) {
  int i = blockIdx.x * 256 + threadIdx.x;
  if (i < GG) o[i] = a[i] + b[i];
}

// ---------------- mean_word[b][s] = mean over (4 layers, 768) --------------
__global__ void k_meanword(const float* __restrict__ hs, float* __restrict__ mw) {
  int blk = blockIdx.x;           // b*256 + s
  int b = blk >> 8, s = blk & 255;
  __shared__ float red[256];
  size_t base = ((size_t)b * SS + s) * EE;
  const size_t LSTR = (size_t)BB * SS * EE;
  float acc = 0.f;
  for (int l = 0; l < 4; l++)
    for (int e = threadIdx.x; e < EE; e += 256) acc += hs[l * LSTR + base + e];
  red[threadIdx.x] = acc;
  __syncthreads();
  for (int s2 = 128; s2 > 0; s2 >>= 1) {
    if (threadIdx.x < s2) red[threadIdx.x] += red[threadIdx.x + s2];
    __syncthreads();
  }
  if (threadIdx.x == 0) mw[blk] = red[0] * (1.f / 3072.f);
}

// ---------------- idx_pred[b] = argmax (first max) of predicates -----------
__global__ void k_idxpred(const int* __restrict__ pred, int* __restrict__ idxp) {
  int b = blockIdx.x, l = threadIdx.x;  // 64 threads
  const int* pb = pred + b * SS;
  int4 v = *(const int4*)(pb + l * 4);
  int loc = 0x7fffffff;
  if (v.w == 1) loc = 4 * l + 3;
  if (v.z == 1) loc = 4 * l + 2;
  if (v.y == 1) loc = 4 * l + 1;
  if (v.x == 1) loc = 4 * l + 0;
  for (int off = 32; off > 0; off >>= 1) {
    int o = __shfl_down(loc, off);
    loc = min(loc, o);
  }
  if (l == 0) idxp[b] = (loc == 0x7fffffff) ? 0 : loc;
}

// ---------------- A0 [s*32+b][800] bf16 feature matrix ---------------------
__global__ void k_buildA0(const float* __restrict__ hs, const float* __restrict__ mw,
                          const int* __restrict__ idxp, const int* __restrict__ roles,
                          unsigned short* __restrict__ A0) {
  int blk = blockIdx.x;           // s*32 + b
  int s = blk >> 5, b = blk & 31;
  unsigned short* row = A0 + (size_t)blk * 800;
  size_t base = ((size_t)b * SS + s) * EE;
  const size_t LSTR = (size_t)BB * SS * EE;
  for (int k = threadIdx.x; k < EE; k += 256) {
    float v = hs[base + k] + hs[base + LSTR + k] + hs[base + 2 * LSTR + k] + hs[base + 3 * LSTR + k];
    row[k] = f2bf(v * 0.25f);
  }
  if (threadIdx.x == 0) {
    float d = mw[b * SS + s] - mw[b * SS + idxp[b]];
    row[768] = f2bf(d);
    int rl = roles[b * SS + s];
    row[769] = f2bf((rl != 0 && rl != -100) ? 1.f : 0.f);
  }
  if (threadIdx.x < 30) row[770 + threadIdx.x] = 0;
}

// ---------------- GEMM-BT: C[s][n][b] = A[s*32+b][:] . W[n][:] + bias[n] ---
// A: [8192, K] bf16 ; W: [2048, K] bf16 ; C: fp32 [256][2048][32]
__global__ __launch_bounds__(256) void k_gemm_bt(const unsigned short* __restrict__ A,
                                                 const unsigned short* __restrict__ W,
                                                 const float* __restrict__ bias,
                                                 float* __restrict__ C, int K) {
  __shared__ unsigned short As[128 * 32];
  __shared__ unsigned short Bs[128 * 32];
  const int tid = threadIdx.x;
  const int wave = tid >> 6, lane = tid & 63;
  const int l15 = lane & 15, quad = lane >> 4;
  const int m0 = blockIdx.y * 128, n0 = blockIdx.x * 128;
  const int wr = (wave >> 1) * 64, wc = (wave & 1) * 64;
  const int srow = wave * 16 + (lane >> 2);
  const int scol = (lane & 3) * 8;

  f32x4 acc[4][4];
#pragma unroll
  for (int i = 0; i < 4; i++)
#pragma unroll
    for (int j = 0; j < 4; j++) acc[i][j] = (f32x4){0.f, 0.f, 0.f, 0.f};

  for (int k0 = 0; k0 < K; k0 += 32) {
#pragma unroll
    for (int rep = 0; rep < 2; rep++) {
      load_lds16(A + (size_t)(m0 + rep * 64 + srow) * K + k0 + scol,
                 &As[(rep * 64 + wave * 16) * 32]);
      load_lds16(W + (size_t)(n0 + rep * 64 + srow) * K + k0 + scol,
                 &Bs[(rep * 64 + wave * 16) * 32]);
    }
    __syncthreads();
    bf16x8 af[4], bfr[4];
#pragma unroll
    for (int i = 0; i < 4; i++) af[i] = *(const bf16x8*)&As[(wr + i * 16 + l15) * 32 + quad * 8];
#pragma unroll
    for (int j = 0; j < 4; j++) bfr[j] = *(const bf16x8*)&Bs[(wc + j * 16 + l15) * 32 + quad * 8];
#pragma unroll
    for (int i = 0; i < 4; i++)
#pragma unroll
      for (int j = 0; j < 4; j++)
        acc[i][j] = __builtin_amdgcn_mfma_f32_16x16x32_bf16(af[i], bfr[j], acc[i][j], 0, 0, 0);
    __syncthreads();
  }

#pragma unroll
  for (int j = 0; j < 4; j++) {
    int n = n0 + wc + j * 16 + l15;
    float bv = bias[n];
#pragma unroll
    for (int i = 0; i < 4; i++) {
      int m = m0 + wr + i * 16 + quad * 4;  // row = s*32+b, 4 consecutive b
      int s = m >> 5, b = m & 31;
      f32x4 v = acc[i][j];
      f32x4 outv = {v[0] + bv, v[1] + bv, v[2] + bv, v[3] + bv};
      *(f32x4*)(C + ((size_t)s * GG + n) * BB + b) = outv;
    }
  }
}

// ---------------- persistent BiLSTM recurrence (one layer) ------------------
// 32 WGs: dir = wg>>4 (0 fwd, 1 bwd), slice = wg&15 -> hidden units [32*slice, +32)
// wave w handles gate type w (i,f,g,o), rows w*512 + u0 + [0,32)
// Cross-WG sync: per-WG epoch flags (release store + parallel poll), NOT a
// shared atomic counter — 32 serialized device-scope RMWs cost ~16us/step (R1).
__global__ __launch_bounds__(256) void k_recurrent(const float* __restrict__ xWf,
                                                   const float* __restrict__ xWb,
                                                   const unsigned short* __restrict__ WhhF,
                                                   const unsigned short* __restrict__ WhhB,
                                                   unsigned short* __restrict__ hbuf,
                                                   unsigned short* __restrict__ Hout,
                                                   int* __restrict__ flags) {
  const int wg = blockIdx.x, dir = wg >> 4, slice = wg & 15;
  const int tid = threadIdx.x, wave = tid >> 6, lane = tid & 63;
  const int l15 = lane & 15, quad = lane >> 4;
  const int u0 = slice * 32;
  const unsigned short* Whh = dir ? WhhB : WhhF;
  const float* xW = dir ? xWb : xWf;
  unsigned short* hb = hbuf + dir * (2 * BB * HH);
  int* flg = flags + dir * (NWG * 32);

  // Whh B-fragments resident in registers: 2 n-tiles x 16 k-steps = 128 VGPRs
  bf16x8 bfrag[2][16];
#pragma unroll
  for (int j = 0; j < 2; j++) {
    const unsigned short* wrow = Whh + (size_t)(wave * HH + u0 + j * 16 + l15) * HH + quad * 8;
#pragma unroll
    for (int kk = 0; kk < 16; kk++) bfrag[j][kk] = *(const bf16x8*)(wrow + kk * 32);
  }

  __shared__ float gbuf[4][32][32];  // [gate][batch][unit_local]
  const int cb = tid >> 3;           // batch this thread updates (32)
  const int cu = (tid & 7) * 4;      // 4 consecutive local units
  float cst[4] = {0.f, 0.f, 0.f, 0.f};

  // prefetch xW for t=0 (acc init values)
  f32x4 xv[2][2];
  {
    const int time0 = dir ? (SS - 1) : 0;
#pragma unroll
    for (int j = 0; j < 2; j++)
#pragma unroll
      for (int i = 0; i < 2; i++)
        xv[i][j] = *(const f32x4*)(xW + ((size_t)time0 * GG + wave * HH + u0 + j * 16 + l15) * BB +
                                   i * 16 + quad * 4);
  }

  for (int t = 0; t < SS; t++) {
    const int par = t & 1;
    const int time = dir ? (SS - 1 - t) : t;
    const unsigned short* hsrc = hb + par * BB * HH;

    f32x4 acc[2][2];
#pragma unroll
    for (int i = 0; i < 2; i++)
#pragma unroll
      for (int j = 0; j < 2; j++) acc[i][j] = xv[i][j];

    const unsigned short* ap0 = hsrc + l15 * HH + quad * 8;
    const unsigned short* ap1 = hsrc + (16 + l15) * HH + quad * 8;
#pragma unroll
    for (int kk = 0; kk < 16; kk++) {
      bf16x8 a0 = *(const bf16x8*)(ap0 + kk * 32);
      bf16x8 a1 = *(const bf16x8*)(ap1 + kk * 32);
      acc[0][0] = __builtin_amdgcn_mfma_f32_16x16x32_bf16(a0, bfrag[0][kk], acc[0][0], 0, 0, 0);
      acc[0][1] = __builtin_amdgcn_mfma_f32_16x16x32_bf16(a0, bfrag[1][kk], acc[0][1], 0, 0, 0);
      acc[1][0] = __builtin_amdgcn_mfma_f32_16x16x32_bf16(a1, bfrag[0][kk], acc[1][0], 0, 0, 0);
      acc[1][1] = __builtin_amdgcn_mfma_f32_16x16x32_bf16(a1, bfrag[1][kk], acc[1][1], 0, 0, 0);
    }
#pragma unroll
    for (int i = 0; i < 2; i++)
#pragma unroll
      for (int j = 0; j < 2; j++)
#pragma unroll
        for (int r = 0; r < 4; r++)
          gbuf[wave][i * 16 + quad * 4 + r][j * 16 + l15] = acc[i][j][r];
    __syncthreads();

    // cell update: thread owns (cb, u0+cu .. +3)
    f32x4 G0 = *(const f32x4*)&gbuf[0][cb][cu];
    f32x4 G1 = *(const f32x4*)&gbuf[1][cb][cu];
    f32x4 G2 = *(const f32x4*)&gbuf[2][cb][cu];
    f32x4 G3 = *(const f32x4*)&gbuf[3][cb][cu];
    unsigned short hs4[4];
#pragma unroll
    for (int q = 0; q < 4; q++) {
      float gi = sigm(G0[q]), gf = sigm(G1[q]), gg = tanhf(G2[q]), go = sigm(G3[q]);
      cst[q] = gf * cst[q] + gi * gg;
      hs4[q] = f2bf(go * tanhf(cst[q]));
    }
    uint2 packed;
    packed.x = (unsigned int)hs4[0] | ((unsigned int)hs4[1] << 16);
    packed.y = (unsigned int)hs4[2] | ((unsigned int)hs4[3] << 16);
    *(uint2*)(hb + (1 - par) * BB * HH + cb * HH + u0 + cu) = packed;

    __threadfence();
    __syncthreads();
    if (tid == 0)
      __hip_atomic_store(&flg[slice * 32], t + 1, __ATOMIC_RELEASE, __HIP_MEMORY_SCOPE_AGENT);

    // off the critical path: Hout store + next-step xW prefetch overlap the poll
    *(uint2*)(Hout + ((size_t)time * BB + cb) * 1024 + dir * HH + u0 + cu) = packed;
    {
      const int tn = (t + 1 < SS) ? (t + 1) : t;
      const int timen = dir ? (SS - 1 - tn) : tn;
#pragma unroll
      for (int j = 0; j < 2; j++)
#pragma unroll
        for (int i = 0; i < 2; i++)
          xv[i][j] = *(const f32x4*)(xW + ((size_t)timen * GG + wave * HH + u0 + j * 16 + l15) * BB +
                                     i * 16 + quad * 4);
    }

    if (wave == 0) {
      const int need = t + 1;
      for (;;) {
        int v = (lane < NWG)
                    ? __hip_atomic_load(&flg[lane * 32], __ATOMIC_RELAXED, __HIP_MEMORY_SCOPE_AGENT)
                    : need;
        if (__all(v >= need)) break;
      }
    }
    __syncthreads();
    __threadfence();
  }
}

// ---------------- final linear: out[b][s][c] = H1[s*32+b][:] . Wout[c][:] + bout[c]
__global__ __launch_bounds__(256) void k_out(const unsigned short* __restrict__ H1,
                                             const float* __restrict__ Wout,
                                             const float* __restrict__ bout,
                                             float* __restrict__ out) {
  __shared__ float rows[8][1024];
  __shared__ float ps[8][32][8];  // [kpart][class][row]
  const int rb = blockIdx.x * 8;
  const int tid = threadIdx.x;
  for (int idx = tid; idx < 8 * 1024; idx += 256) {
    int r = idx >> 10, k = idx & 1023;
    rows[r][k] = bf2f(H1[(size_t)(rb + r) * 1024 + k]);
  }
  __syncthreads();
  const int c = tid & 31, p = tid >> 5;
  float acc[8] = {0.f, 0.f, 0.f, 0.f, 0.f, 0.f, 0.f, 0.f};
  if (c < NCLS) {
    const float* wr = Wout + (size_t)c * 1024 + p * 128;
    for (int k = 0; k < 128; k++) {
      float w = wr[k];
#pragma unroll
      for (int r = 0; r < 8; r++) acc[r] += rows[r][p * 128 + k] * w;
    }
  }
#pragma unroll
  for (int r = 0; r < 8; r++) ps[p][c][r] = acc[r];
  __syncthreads();
  if (p == 0 && c < NCLS) {
    for (int r = 0; r < 8; r++) {
      float v = bout[c];
#pragma unroll
      for (int q = 0; q < 8; q++) v += ps[q][c][r];
      int row = rb + r, s = row >> 5, b = row & 31;
      out[((size_t)b * SS + s) * NCLS + c] = v;
    }
  }
}

// ---------------------------------------------------------------------------
extern "C" void kernel_launch(void* const* d_in, const int* in_sizes, int n_in,
                              void* d_out, int out_size, void* d_ws, size_t ws_size,
                              hipStream_t stream) {
  const float* hs     = (const float*)d_in[0];
  const int*   roles  = (const int*)d_in[1];
  const int*   preds  = (const int*)d_in[2];
  const float* Wih0f  = (const float*)d_in[3];
  const float* Whh0f  = (const float*)d_in[4];
  const float* bih0f  = (const float*)d_in[5];
  const float* bhh0f  = (const float*)d_in[6];
  const float* Wih0b  = (const float*)d_in[7];
  const float* Whh0b  = (const float*)d_in[8];
  const float* bih0b  = (const float*)d_in[9];
  const float* bhh0b  = (const float*)d_in[10];
  const float* Wih1f  = (const float*)d_in[11];
  const float* Whh1f  = (const float*)d_in[12];
  const float* bih1f  = (const float*)d_in[13];
  const float* bhh1f  = (const float*)d_in[14];
  const float* Wih1b  = (const float*)d_in[15];
  const float* Whh1b  = (const float*)d_in[16];
  const float* bih1b  = (const float*)d_in[17];
  const float* bhh1b  = (const float*)d_in[18];
  const float* Wout   = (const float*)d_in[19];
  const float* bout   = (const float*)d_in[20];
  (void)in_sizes; (void)n_in; (void)out_size; (void)ws_size;

  char* ws = (char*)d_ws;
  size_t off = 0;
  auto alloc = [&](size_t bytes) -> char* {
    char* p = ws + off;
    off += (bytes + 255) & ~(size_t)255;
    return p;
  };
  float* xWf = (float*)alloc((size_t)SS * GG * BB * 4);       // 67.1 MB (reused L0/L1)
  float* xWb = (float*)alloc((size_t)SS * GG * BB * 4);       // 67.1 MB
  unsigned short* A0  = (unsigned short*)alloc((size_t)8192 * 800 * 2);
  unsigned short* H0p = (unsigned short*)alloc((size_t)8192 * 1024 * 2);
  unsigned short* H1p = (unsigned short*)alloc((size_t)8192 * 1024 * 2);
  unsigned short* Wb0f = (unsigned short*)alloc((size_t)GG * 800 * 2);
  unsigned short* Wb0b = (unsigned short*)alloc((size_t)GG * 800 * 2);
  unsigned short* Wb1f = (unsigned short*)alloc((size_t)GG * 1024 * 2);
  unsigned short* Wb1b = (unsigned short*)alloc((size_t)GG * 1024 * 2);
  unsigned short* Wh0f = (unsigned short*)alloc((size_t)GG * HH * 2);
  unsigned short* Wh0b = (unsigned short*)alloc((size_t)GG * HH * 2);
  unsigned short* Wh1f = (unsigned short*)alloc((size_t)GG * HH * 2);
  unsigned short* Wh1b = (unsigned short*)alloc((size_t)GG * HH * 2);
  float* bsum = (float*)alloc(4 * GG * 4);
  float* mw   = (float*)alloc((size_t)BB * SS * 4);
  int*   idxp = (int*)alloc(256);
  // zeroed region: h double-buffers (128KB per layer) + epoch flags (4KB/layer)
  char*  zbase = alloc(131072 + 131072 + 8192);
  unsigned short* hbuf0 = (unsigned short*)zbase;
  unsigned short* hbuf1 = (unsigned short*)(zbase + 131072);
  int* flags0 = (int*)(zbase + 262144);
  int* flags1 = (int*)(zbase + 262144 + 4096);

  hipMemsetAsync(zbase, 0, 131072 + 131072 + 8192, stream);

  k_convpad<<<1024, 256, 0, stream>>>(Wih0f, Wb0f, GG, 770, 800);
  k_convpad<<<1024, 256, 0, stream>>>(Wih0b, Wb0b, GG, 770, 800);
  k_convpad<<<1024, 256, 0, stream>>>(Wih1f, Wb1f, GG, 1024, 1024);
  k_convpad<<<1024, 256, 0, stream>>>(Wih1b, Wb1b, GG, 1024, 1024);
  k_convpad<<<1024, 256, 0, stream>>>(Whh0f, Wh0f, GG, 512, 512);
  k_convpad<<<1024, 256, 0, stream>>>(Whh0b, Wh0b, GG, 512, 512);
  k_convpad<<<1024, 256, 0, stream>>>(Whh1f, Wh1f, GG, 512, 512);
  k_convpad<<<1024, 256, 0, stream>>>(Whh1b, Wh1b, GG, 512, 512);
  k_biassum<<<8, 256, 0, stream>>>(bih0f, bhh0f, bsum);
  k_biassum<<<8, 256, 0, stream>>>(bih0b, bhh0b, bsum + 2048);
  k_biassum<<<8, 256, 0, stream>>>(bih1f, bhh1f, bsum + 4096);
  k_biassum<<<8, 256, 0, stream>>>(bih1b, bhh1b, bsum + 6144);

  k_meanword<<<BB * SS, 256, 0, stream>>>(hs, mw);
  k_idxpred<<<BB, 64, 0, stream>>>(preds, idxp);
  k_buildA0<<<BB * SS, 256, 0, stream>>>(hs, mw, idxp, roles, A0);

  dim3 gg(16, 64);
  k_gemm_bt<<<gg, 256, 0, stream>>>(A0, Wb0f, bsum, xWf, 800);
  k_gemm_bt<<<gg, 256, 0, stream>>>(A0, Wb0b, bsum + 2048, xWb, 800);
  k_recurrent<<<2 * NWG, 256, 0, stream>>>(xWf, xWb, Wh0f, Wh0b, hbuf0, H0p, flags0);
  k_gemm_bt<<<gg, 256, 0, stream>>>(H0p, Wb1f, bsum + 4096, xWf, 1024);
  k_gemm_bt<<<gg, 256, 0, stream>>>(H0p, Wb1b, bsum + 6144, xWb, 1024);
  k_recurrent<<<2 * NWG, 256, 0, stream>>>(xWf, xWb, Wh1f, Wh1b, hbuf1, H1p, flags1);
  k_out<<<1024, 256, 0, stream>>>(H1p, Wout, bout, (float*)d_out);
}

// Round 3
// 4670.563 us; speedup vs baseline: 1.9635x; 1.5794x over previous
//
#include <hip/hip_runtime.h>
#include <hip/hip_bf16.h>
#include <math.h>

#define BB 32
#define SS 256
#define EE 768
#define HH 512
#define GG 2048   // 4*H
#define NCLS 30
#define NWG 16    // workgroups per LSTM direction

typedef __attribute__((ext_vector_type(8))) short bf16x8;
typedef __attribute__((ext_vector_type(4))) float f32x4;

__device__ inline unsigned short f2bf(float f) {
  union { float f; unsigned int u; } v; v.f = f;
  unsigned int r = v.u + 0x7fffu + ((v.u >> 16) & 1u);
  return (unsigned short)(r >> 16);
}
__device__ inline float bf2f(unsigned short u) {
  union { unsigned int u; float f; } v; v.u = ((unsigned int)u) << 16;
  return v.f;
}
__device__ inline float sigm(float x) { return 1.f / (1.f + expf(-x)); }

__device__ inline void load_lds16(const void* g, void* l) {
  __builtin_amdgcn_global_load_lds(
      (const __attribute__((address_space(1))) void*)g,
      (__attribute__((address_space(3))) void*)l, 16, 0, 0);
}

// --- coherent (write-through, L2-bypass) ops for cross-WG h/flag exchange ---
__device__ inline void store_coh64(void* p, unsigned long long v) {
  unsigned long long a = (unsigned long long)p;
  asm volatile("global_store_dwordx2 %0, %1, off sc0 sc1" :: "v"(a), "v"(v) : "memory");
}
__device__ inline void store_coh32(void* p, int v) {
  unsigned long long a = (unsigned long long)p;
  asm volatile("global_store_dword %0, %1, off sc0 sc1" :: "v"(a), "v"(v) : "memory");
}
__device__ inline int load_coh32(const void* p) {
  unsigned long long a = (unsigned long long)p;
  int v;
  asm volatile("global_load_dword %0, %1, off sc0 sc1\n\ts_waitcnt vmcnt(0)"
               : "=v"(v) : "v"(a) : "memory");
  return v;
}
__device__ inline void wait_vm0() {
  asm volatile("s_waitcnt vmcnt(0)" ::: "memory");
}

// ---------------- weight conversion (fp32 -> bf16, with K padding) ----------
__global__ void k_convpad(const float* __restrict__ src, unsigned short* __restrict__ dst,
                          int R, int Ks, int Kd) {
  int n = R * Kd;
  for (int i = blockIdx.x * blockDim.x + threadIdx.x; i < n; i += gridDim.x * blockDim.x) {
    int r = i / Kd, k = i - r * Kd;
    dst[i] = (k < Ks) ? f2bf(src[(size_t)r * Ks + k]) : (unsigned short)0;
  }
}

__global__ void k_biassum(const float* __restrict__ a, const float* __restrict__ b,
                          float* __restrict__ o) {
  int i = blockIdx.x * 256 + threadIdx.x;
  if (i < GG) o[i] = a[i] + b[i];
}

// ---------------- mean_word[b][s] = mean over (4 layers, 768) --------------
__global__ void k_meanword(const float* __restrict__ hs, float* __restrict__ mw) {
  int blk = blockIdx.x;           // b*256 + s
  int b = blk >> 8, s = blk & 255;
  __shared__ float red[256];
  size_t base = ((size_t)b * SS + s) * EE;
  const size_t LSTR = (size_t)BB * SS * EE;
  float acc = 0.f;
  for (int l = 0; l < 4; l++)
    for (int e = threadIdx.x; e < EE; e += 256) acc += hs[l * LSTR + base + e];
  red[threadIdx.x] = acc;
  __syncthreads();
  for (int s2 = 128; s2 > 0; s2 >>= 1) {
    if (threadIdx.x < s2) red[threadIdx.x] += red[threadIdx.x + s2];
    __syncthreads();
  }
  if (threadIdx.x == 0) mw[blk] = red[0] * (1.f / 3072.f);
}

// ---------------- idx_pred[b] = argmax (first max) of predicates -----------
__global__ void k_idxpred(const int* __restrict__ pred, int* __restrict__ idxp) {
  int b = blockIdx.x, l = threadIdx.x;  // 64 threads
  const int* pb = pred + b * SS;
  int4 v = *(const int4*)(pb + l * 4);
  int loc = 0x7fffffff;
  if (v.w == 1) loc = 4 * l + 3;
  if (v.z == 1) loc = 4 * l + 2;
  if (v.y == 1) loc = 4 * l + 1;
  if (v.x == 1) loc = 4 * l + 0;
  for (int off = 32; off > 0; off >>= 1) {
    int o = __shfl_down(loc, off);
    loc = min(loc, o);
  }
  if (l == 0) idxp[b] = (loc == 0x7fffffff) ? 0 : loc;
}

// ---------------- A0 [s*32+b][800] bf16 feature matrix ---------------------
__global__ void k_buildA0(const float* __restrict__ hs, const float* __restrict__ mw,
                          const int* __restrict__ idxp, const int* __restrict__ roles,
                          unsigned short* __restrict__ A0) {
  int blk = blockIdx.x;           // s*32 + b
  int s = blk >> 5, b = blk & 31;
  unsigned short* row = A0 + (size_t)blk * 800;
  size_t base = ((size_t)b * SS + s) * EE;
  const size_t LSTR = (size_t)BB * SS * EE;
  for (int k = threadIdx.x; k < EE; k += 256) {
    float v = hs[base + k] + hs[base + LSTR + k] + hs[base + 2 * LSTR + k] + hs[base + 3 * LSTR + k];
    row[k] = f2bf(v * 0.25f);
  }
  if (threadIdx.x == 0) {
    float d = mw[b * SS + s] - mw[b * SS + idxp[b]];
    row[768] = f2bf(d);
    int rl = roles[b * SS + s];
    row[769] = f2bf((rl != 0 && rl != -100) ? 1.f : 0.f);
  }
  if (threadIdx.x < 30) row[770 + threadIdx.x] = 0;
}

// ---------------- GEMM-BT: C[s][n][b] = A[s*32+b][:] . W[n][:] + bias[n] ---
// A: [8192, K] bf16 ; W: [2048, K] bf16 ; C: fp32 [256][2048][32]
__global__ __launch_bounds__(256) void k_gemm_bt(const unsigned short* __restrict__ A,
                                                 const unsigned short* __restrict__ W,
                                                 const float* __restrict__ bias,
                                                 float* __restrict__ C, int K) {
  __shared__ unsigned short As[128 * 32];
  __shared__ unsigned short Bs[128 * 32];
  const int tid = threadIdx.x;
  const int wave = tid >> 6, lane = tid & 63;
  const int l15 = lane & 15, quad = lane >> 4;
  const int m0 = blockIdx.y * 128, n0 = blockIdx.x * 128;
  const int wr = (wave >> 1) * 64, wc = (wave & 1) * 64;
  const int srow = wave * 16 + (lane >> 2);
  const int scol = (lane & 3) * 8;

  f32x4 acc[4][4];
#pragma unroll
  for (int i = 0; i < 4; i++)
#pragma unroll
    for (int j = 0; j < 4; j++) acc[i][j] = (f32x4){0.f, 0.f, 0.f, 0.f};

  for (int k0 = 0; k0 < K; k0 += 32) {
#pragma unroll
    for (int rep = 0; rep < 2; rep++) {
      load_lds16(A + (size_t)(m0 + rep * 64 + srow) * K + k0 + scol,
                 &As[(rep * 64 + wave * 16) * 32]);
      load_lds16(W + (size_t)(n0 + rep * 64 + srow) * K + k0 + scol,
                 &Bs[(rep * 64 + wave * 16) * 32]);
    }
    __syncthreads();
    bf16x8 af[4], bfr[4];
#pragma unroll
    for (int i = 0; i < 4; i++) af[i] = *(const bf16x8*)&As[(wr + i * 16 + l15) * 32 + quad * 8];
#pragma unroll
    for (int j = 0; j < 4; j++) bfr[j] = *(const bf16x8*)&Bs[(wc + j * 16 + l15) * 32 + quad * 8];
#pragma unroll
    for (int i = 0; i < 4; i++)
#pragma unroll
      for (int j = 0; j < 4; j++)
        acc[i][j] = __builtin_amdgcn_mfma_f32_16x16x32_bf16(af[i], bfr[j], acc[i][j], 0, 0, 0);
    __syncthreads();
  }

#pragma unroll
  for (int j = 0; j < 4; j++) {
    int n = n0 + wc + j * 16 + l15;
    float bv = bias[n];
#pragma unroll
    for (int i = 0; i < 4; i++) {
      int m = m0 + wr + i * 16 + quad * 4;  // row = s*32+b, 4 consecutive b
      int s = m >> 5, b = m & 31;
      f32x4 v = acc[i][j];
      f32x4 outv = {v[0] + bv, v[1] + bv, v[2] + bv, v[3] + bv};
      *(f32x4*)(C + ((size_t)s * GG + n) * BB + b) = outv;
    }
  }
}

// ---------------- persistent BiLSTM recurrence (one layer) ------------------
// 32 WGs: dir = wg>>4, slice = wg&15 -> hidden units [32*slice, +32)
// wave w handles gate type w (i,f,g,o), rows w*512 + u0 + [0,32)
// Cross-WG sync: h + flags go through WRITE-THROUGH coherent stores (sc0 sc1,
// L2-bypass) so NO buffer_wbl2 is ever needed; acquire side is only a cheap
// buffer_inv (R2 showed __threadfence's wbl2 of streaming dirty lines was the
// 13.7us/step floor).
__global__ __launch_bounds__(256) void k_recurrent(const float* __restrict__ xWf,
                                                   const float* __restrict__ xWb,
                                                   const unsigned short* __restrict__ WhhF,
                                                   const unsigned short* __restrict__ WhhB,
                                                   unsigned short* __restrict__ hbuf,
                                                   unsigned short* __restrict__ Hout,
                                                   int* __restrict__ flags) {
  const int wg = blockIdx.x, dir = wg >> 4, slice = wg & 15;
  const int tid = threadIdx.x, wave = tid >> 6, lane = tid & 63;
  const int l15 = lane & 15, quad = lane >> 4;
  const int u0 = slice * 32;
  const unsigned short* Whh = dir ? WhhB : WhhF;
  const float* xW = dir ? xWb : xWf;
  unsigned short* hb = hbuf + dir * (2 * BB * HH);
  int* flg = flags + dir * (NWG * 32);

  // Whh B-fragments resident in registers: 2 n-tiles x 16 k-steps = 128 regs
  bf16x8 bfrag[2][16];
#pragma unroll
  for (int j = 0; j < 2; j++) {
    const unsigned short* wrow = Whh + (size_t)(wave * HH + u0 + j * 16 + l15) * HH + quad * 8;
#pragma unroll
    for (int kk = 0; kk < 16; kk++) bfrag[j][kk] = *(const bf16x8*)(wrow + kk * 32);
  }

  __shared__ float gbuf[4][32][32];  // [gate][batch][unit_local]
  const int cb = tid >> 3;           // batch this thread updates (32)
  const int cu = (tid & 7) * 4;      // 4 consecutive local units
  float cst[4] = {0.f, 0.f, 0.f, 0.f};

  // prefetch xW for t=0 (acc init values)
  f32x4 xv[2][2];
  {
    const int time0 = dir ? (SS - 1) : 0;
#pragma unroll
    for (int j = 0; j < 2; j++)
#pragma unroll
      for (int i = 0; i < 2; i++)
        xv[i][j] = *(const f32x4*)(xW + ((size_t)time0 * GG + wave * HH + u0 + j * 16 + l15) * BB +
                                   i * 16 + quad * 4);
  }

  for (int t = 0; t < SS; t++) {
    const int par = t & 1;
    const int time = dir ? (SS - 1 - t) : t;
    const unsigned short* hsrc = hb + par * BB * HH;

    f32x4 acc[2][2];
#pragma unroll
    for (int i = 0; i < 2; i++)
#pragma unroll
      for (int j = 0; j < 2; j++) acc[i][j] = xv[i][j];

    const unsigned short* ap0 = hsrc + l15 * HH + quad * 8;
    const unsigned short* ap1 = hsrc + (16 + l15) * HH + quad * 8;
#pragma unroll
    for (int kk = 0; kk < 16; kk++) {
      bf16x8 a0 = *(const bf16x8*)(ap0 + kk * 32);
      bf16x8 a1 = *(const bf16x8*)(ap1 + kk * 32);
      acc[0][0] = __builtin_amdgcn_mfma_f32_16x16x32_bf16(a0, bfrag[0][kk], acc[0][0], 0, 0, 0);
      acc[0][1] = __builtin_amdgcn_mfma_f32_16x16x32_bf16(a0, bfrag[1][kk], acc[0][1], 0, 0, 0);
      acc[1][0] = __builtin_amdgcn_mfma_f32_16x16x32_bf16(a1, bfrag[0][kk], acc[1][0], 0, 0, 0);
      acc[1][1] = __builtin_amdgcn_mfma_f32_16x16x32_bf16(a1, bfrag[1][kk], acc[1][1], 0, 0, 0);
    }
#pragma unroll
    for (int i = 0; i < 2; i++)
#pragma unroll
      for (int j = 0; j < 2; j++)
#pragma unroll
        for (int r = 0; r < 4; r++)
          gbuf[wave][i * 16 + quad * 4 + r][j * 16 + l15] = acc[i][j][r];
    __syncthreads();

    // cell update: thread owns (cb, u0+cu .. +3)
    f32x4 G0 = *(const f32x4*)&gbuf[0][cb][cu];
    f32x4 G1 = *(const f32x4*)&gbuf[1][cb][cu];
    f32x4 G2 = *(const f32x4*)&gbuf[2][cb][cu];
    f32x4 G3 = *(const f32x4*)&gbuf[3][cb][cu];
    unsigned short hs4[4];
#pragma unroll
    for (int q = 0; q < 4; q++) {
      float gi = sigm(G0[q]), gf = sigm(G1[q]), gg = tanhf(G2[q]), go = sigm(G3[q]);
      cst[q] = gf * cst[q] + gi * gg;
      hs4[q] = f2bf(go * tanhf(cst[q]));
    }
    unsigned long long packed =
        (unsigned long long)((unsigned int)hs4[0] | ((unsigned int)hs4[1] << 16)) |
        ((unsigned long long)((unsigned int)hs4[2] | ((unsigned int)hs4[3] << 16)) << 32);

    // write-through coherent h store; drain (per-wave) before signaling
    store_coh64(hb + (1 - par) * BB * HH + cb * HH + u0 + cu, packed);
    wait_vm0();
    __syncthreads();
    if (tid == 0) store_coh32(&flg[slice * 32], t + 1);

    // off the critical path: Hout store + next-step xW prefetch overlap the poll
    *(uint2*)(Hout + ((size_t)time * BB + cb) * 1024 + dir * HH + u0 + cu) =
        make_uint2((unsigned int)packed, (unsigned int)(packed >> 32));
    {
      const int tn = (t + 1 < SS) ? (t + 1) : t;
      const int timen = dir ? (SS - 1 - tn) : tn;
#pragma unroll
      for (int j = 0; j < 2; j++)
#pragma unroll
        for (int i = 0; i < 2; i++)
          xv[i][j] = *(const f32x4*)(xW + ((size_t)timen * GG + wave * HH + u0 + j * 16 + l15) * BB +
                                     i * 16 + quad * 4);
    }

    if (wave == 0) {
      const int need = t + 1;
      for (;;) {
        int v = (lane < NWG) ? load_coh32(&flg[lane * 32]) : need;
        if (__all(v >= need)) break;
        __builtin_amdgcn_s_sleep(1);
      }
      // cheap acquire: buffer_inv only (no wbl2) so plain h loads see fresh data
      __builtin_amdgcn_fence(__ATOMIC_ACQUIRE, "agent");
    }
    __syncthreads();
  }
}

// ---------------- final linear: out[b][s][c] = H1[s*32+b][:] . Wout[c][:] + bout[c]
__global__ __launch_bounds__(256) void k_out(const unsigned short* __restrict__ H1,
                                             const float* __restrict__ Wout,
                                             const float* __restrict__ bout,
                                             float* __restrict__ out) {
  __shared__ float rows[8][1024];
  __shared__ float ps[8][32][8];  // [kpart][class][row]
  const int rb = blockIdx.x * 8;
  const int tid = threadIdx.x;
  for (int idx = tid; idx < 8 * 1024; idx += 256) {
    int r = idx >> 10, k = idx & 1023;
    rows[r][k] = bf2f(H1[(size_t)(rb + r) * 1024 + k]);
  }
  __syncthreads();
  const int c = tid & 31, p = tid >> 5;
  float acc[8] = {0.f, 0.f, 0.f, 0.f, 0.f, 0.f, 0.f, 0.f};
  if (c < NCLS) {
    const float* wr = Wout + (size_t)c * 1024 + p * 128;
    for (int k = 0; k < 128; k++) {
      float w = wr[k];
#pragma unroll
      for (int r = 0; r < 8; r++) acc[r] += rows[r][p * 128 + k] * w;
    }
  }
#pragma unroll
  for (int r = 0; r < 8; r++) ps[p][c][r] = acc[r];
  __syncthreads();
  if (p == 0 && c < NCLS) {
    for (int r = 0; r < 8; r++) {
      float v = bout[c];
#pragma unroll
      for (int q = 0; q < 8; q++) v += ps[q][c][r];
      int row = rb + r, s = row >> 5, b = row & 31;
      out[((size_t)b * SS + s) * NCLS + c] = v;
    }
  }
}

// ---------------------------------------------------------------------------
extern "C" void kernel_launch(void* const* d_in, const int* in_sizes, int n_in,
                              void* d_out, int out_size, void* d_ws, size_t ws_size,
                              hipStream_t stream) {
  const float* hs     = (const float*)d_in[0];
  const int*   roles  = (const int*)d_in[1];
  const int*   preds  = (const int*)d_in[2];
  const float* Wih0f  = (const float*)d_in[3];
  const float* Whh0f  = (const float*)d_in[4];
  const float* bih0f  = (const float*)d_in[5];
  const float* bhh0f  = (const float*)d_in[6];
  const float* Wih0b  = (const float*)d_in[7];
  const float* Whh0b  = (const float*)d_in[8];
  const float* bih0b  = (const float*)d_in[9];
  const float* bhh0b  = (const float*)d_in[10];
  const float* Wih1f  = (const float*)d_in[11];
  const float* Whh1f  = (const float*)d_in[12];
  const float* bih1f  = (const float*)d_in[13];
  const float* bhh1f  = (const float*)d_in[14];
  const float* Wih1b  = (const float*)d_in[15];
  const float* Whh1b  = (const float*)d_in[16];
  const float* bih1b  = (const float*)d_in[17];
  const float* bhh1b  = (const float*)d_in[18];
  const float* Wout   = (const float*)d_in[19];
  const float* bout   = (const float*)d_in[20];
  (void)in_sizes; (void)n_in; (void)out_size; (void)ws_size;

  char* ws = (char*)d_ws;
  size_t off = 0;
  auto alloc = [&](size_t bytes) -> char* {
    char* p = ws + off;
    off += (bytes + 255) & ~(size_t)255;
    return p;
  };
  float* xWf = (float*)alloc((size_t)SS * GG * BB * 4);       // 67.1 MB (reused L0/L1)
  float* xWb = (float*)alloc((size_t)SS * GG * BB * 4);       // 67.1 MB
  unsigned short* A0  = (unsigned short*)alloc((size_t)8192 * 800 * 2);
  unsigned short* H0p = (unsigned short*)alloc((size_t)8192 * 1024 * 2);
  unsigned short* H1p = (unsigned short*)alloc((size_t)8192 * 1024 * 2);
  unsigned short* Wb0f = (unsigned short*)alloc((size_t)GG * 800 * 2);
  unsigned short* Wb0b = (unsigned short*)alloc((size_t)GG * 800 * 2);
  unsigned short* Wb1f = (unsigned short*)alloc((size_t)GG * 1024 * 2);
  unsigned short* Wb1b = (unsigned short*)alloc((size_t)GG * 1024 * 2);
  unsigned short* Wh0f = (unsigned short*)alloc((size_t)GG * HH * 2);
  unsigned short* Wh0b = (unsigned short*)alloc((size_t)GG * HH * 2);
  unsigned short* Wh1f = (unsigned short*)alloc((size_t)GG * HH * 2);
  unsigned short* Wh1b = (unsigned short*)alloc((size_t)GG * HH * 2);
  float* bsum = (float*)alloc(4 * GG * 4);
  float* mw   = (float*)alloc((size_t)BB * SS * 4);
  int*   idxp = (int*)alloc(256);
  // zeroed region: h double-buffers (128KB per layer) + epoch flags (4KB/layer)
  char*  zbase = alloc(131072 + 131072 + 8192);
  unsigned short* hbuf0 = (unsigned short*)zbase;
  unsigned short* hbuf1 = (unsigned short*)(zbase + 131072);
  int* flags0 = (int*)(zbase + 262144);
  int* flags1 = (int*)(zbase + 262144 + 4096);

  hipMemsetAsync(zbase, 0, 131072 + 131072 + 8192, stream);

  k_convpad<<<1024, 256, 0, stream>>>(Wih0f, Wb0f, GG, 770, 800);
  k_convpad<<<1024, 256, 0, stream>>>(Wih0b, Wb0b, GG, 770, 800);
  k_convpad<<<1024, 256, 0, stream>>>(Wih1f, Wb1f, GG, 1024, 1024);
  k_convpad<<<1024, 256, 0, stream>>>(Wih1b, Wb1b, GG, 1024, 1024);
  k_convpad<<<1024, 256, 0, stream>>>(Whh0f, Wh0f, GG, 512, 512);
  k_convpad<<<1024, 256, 0, stream>>>(Whh0b, Wh0b, GG, 512, 512);
  k_convpad<<<1024, 256, 0, stream>>>(Whh1f, Wh1f, GG, 512, 512);
  k_convpad<<<1024, 256, 0, stream>>>(Whh1b, Wh1b, GG, 512, 512);
  k_biassum<<<8, 256, 0, stream>>>(bih0f, bhh0f, bsum);
  k_biassum<<<8, 256, 0, stream>>>(bih0b, bhh0b, bsum + 2048);
  k_biassum<<<8, 256, 0, stream>>>(bih1f, bhh1f, bsum + 4096);
  k_biassum<<<8, 256, 0, stream>>>(bih1b, bhh1b, bsum + 6144);

  k_meanword<<<BB * SS, 256, 0, stream>>>(hs, mw);
  k_idxpred<<<BB, 64, 0, stream>>>(preds, idxp);
  k_buildA0<<<BB * SS, 256, 0, stream>>>(hs, mw, idxp, roles, A0);

  dim3 gg(16, 64);
  k_gemm_bt<<<gg, 256, 0, stream>>>(A0, Wb0f, bsum, xWf, 800);
  k_gemm_bt<<<gg, 256, 0, stream>>>(A0, Wb0b, bsum + 2048, xWb, 800);
  k_recurrent<<<2 * NWG, 256, 0, stream>>>(xWf, xWb, Wh0f, Wh0b, hbuf0, H0p, flags0);
  k_gemm_bt<<<gg, 256, 0, stream>>>(H0p, Wb1f, bsum + 4096, xWf, 1024);
  k_gemm_bt<<<gg, 256, 0, stream>>>(H0p, Wb1b, bsum + 6144, xWb, 1024);
  k_recurrent<<<2 * NWG, 256, 0, stream>>>(xWf, xWb, Wh1f, Wh1b, hbuf1, H1p, flags1);
  k_out<<<1024, 256, 0, stream>>>(H1p, Wout, bout, (float*)d_out);
}